// Round 9
// baseline (647.457 us; speedup 1.0000x reference)
//
#include <hip/hip_runtime.h>
#include <math.h>

#define TT 512
#define CH 8
#define NCH 64
#define NB 128
#define NGRP 8
#define GSZ (NB/NGRP)
#define ST 36
#define MS 1152
#define LOG2PI 1.8378770664093453

static_assert(TT == CH * NCH, "chunking");

// ---------------- workspace layout (float offsets, global stride 32) ----------------
enum : int {
  WS_X     = 0,
  WS_BCOV  = WS_X    + TT*1024,
  WS_BA    = WS_BCOV + TT*1024,
  WS_YT    = WS_BA   + TT*32,
  WS_MTP   = WS_YT   + TT*32,
  WS_MEP   = WS_MTP + 1024,
  WS_MPP   = WS_MEP + 1024,
  WS_QI    = WS_MPP + 1024,
  WS_RI    = WS_QI  + 1024,
  WS_P0I   = WS_RI  + 1024,
  WS_QIW   = WS_P0I + 1024,
  WS_CW    = WS_QIW + 1024,
  WS_HTRI  = WS_CW  + 1024,
  WS_HTRIH = WS_HTRI+ 1024,
  WS_TQ    = WS_HTRIH+1024,
  WS_EM    = WS_TQ  + 1024,
  WS_EML   = WS_EM  + 1024,
  WS_LAM0CW= WS_EML + 1024,
  WS_QHC   = WS_LAM0CW + 1024,
  WS_C1    = WS_QHC + 1024,
  WS_EMM   = WS_C1  + 1024,
  WS_S1    = WS_EMM + 1024,
  WS_FPT   = WS_S1  + 1024,
  WS_ETA0  = WS_FPT + 1024,
  WS_CTB   = WS_ETA0 + 32,
  WS_QIVTB = WS_CTB + 32,
  WS_FMT   = WS_QIVTB + 32,
  WS_ETAF  = WS_FMT + 32,
  WS_LDS3  = WS_ETAF + 32,
  WS_DACC  = WS_LDS3 + 4,
  WS_Z512  = WS_DACC + 8,
  WS_OPS   = WS_Z512 + 1024,
  WS_GBAR  = WS_OPS + 6*3072,
  WS_PART  = WS_GBAR + 4352,
  WS_ETA_A = WS_PART + 416,
  WS_ETA_B = WS_ETA_A + NCH*1056,
  WS_CEA   = WS_ETA_B + NCH*1056,
  WS_CEB   = WS_CEA + NCH*2048,
  WS_END   = WS_CEB + NCH*2048
};
static_assert(WS_DACC % 2 == 0 && WS_PART % 2 == 0, "double alignment");

// ---------------- helpers ----------------
__device__ __forceinline__ float rlane(float v, int l) {
  return __uint_as_float(__builtin_amdgcn_readlane(__float_as_uint(v), l));
}
__device__ __forceinline__ float dot4(const float4 a, const float4 b) {
  return a.x*b.x + a.y*b.y + a.z*b.z + a.w*b.w;
}
__device__ __forceinline__ float f4c(const float4 v, int e) {
  switch (e) { case 0: return v.x; case 1: return v.y; case 2: return v.z; default: return v.w; }
}

__device__ __forceinline__ double gj_inv32(float a[32]) {
  double pp = 1.0;
#pragma unroll
  for (int p = 0; p < 32; ++p) {
    const float piv = rlane(a[p], p);
    pp *= (double)piv;
    const float sc = a[p] * (1.0f / piv);
#pragma unroll
    for (int r = 0; r < 32; ++r) {
      if (r != p) a[r] -= rlane(a[r], p) * sc;
    }
    a[p] = sc;
  }
  return pp;
}

__device__ __forceinline__ double wave_inv36(float* M, int tid) {
  float a[32]; const int cc = tid & 31;
#pragma unroll
  for (int r = 0; r < 32; ++r)
    a[r] = (tid < 32) ? M[r*ST + cc] : ((r == tid - 32) ? 1.f : 0.f);
  const double pp = gj_inv32(a);
  if (tid >= 32) {
    const int c2 = tid - 32;
#pragma unroll
    for (int r = 0; r < 32; ++r) M[r*ST + c2] = a[r];
  }
  return pp;
}

__device__ __forceinline__ float block_reduce(float v, float* red, int tid) {
#pragma unroll
  for (int m = 32; m >= 1; m >>= 1) v += __shfl_xor(v, m, 64);
  if ((tid & 63) == 0) red[tid >> 6] = v;
  __syncthreads();
  return red[0] + red[1] + red[2] + red[3];
}

__device__ __forceinline__ void stage_mat(const float* __restrict__ g, float* L, int tid) {
  const int r = tid >> 3, c = (tid & 7) * 4;
  *(float4*)(L + r*ST + c) = *(const float4*)(g + r*32 + c);
}
__device__ __forceinline__ void destage_mat(const float* L, float* __restrict__ g, int tid) {
  const int r = tid >> 3, c = (tid & 7) * 4;
  *(float4*)(g + r*32 + c) = *(const float4*)(L + r*ST + c);
}

// ---- legacy 256-thread matmuls (kept for non-critical paths) ----
__device__ __forceinline__ void mm_p(const float* A, const float* B, float* C, int tid) {
  const int ri = tid >> 3, j4 = (tid & 7) * 4;
  float4 acc = {0.f,0.f,0.f,0.f};
#pragma unroll 8
  for (int k = 0; k < 32; ++k) {
    const float a = A[ri*ST + k];
    const float4 b = *(const float4*)(B + k*ST + j4);
    acc.x += a*b.x; acc.y += a*b.y; acc.z += a*b.z; acc.w += a*b.w;
  }
  *(float4*)(C + ri*ST + j4) = acc;
}

// ---- w44 family: ONE WAVE (64 lanes) computes one 32x32 matmul via 4x4 tiles ----
// lane mapping: rows r0..r0+3 (r0 = (lane>>3)*4), cols c0..c0+3 (c0 = (lane&7)*4).
// k-chunk rotation by (lane&7) spreads LDS bank pressure; sum reassociation only.
__device__ __forceinline__ void w44_rr(const float* A, const float* B, float* C, int lane) {
  const int r0 = (lane >> 3) * 4, c0 = (lane & 7) * 4, o = lane & 7;
  float acc[4][4] = {};
#pragma unroll
  for (int kk = 0; kk < 8; ++kk) {
    const int k4 = 4 * ((kk + o) & 7);
    float4 a[4], b[4];
#pragma unroll
    for (int i = 0; i < 4; ++i) a[i] = *(const float4*)(A + (r0+i)*ST + k4);
#pragma unroll
    for (int jj = 0; jj < 4; ++jj) b[jj] = *(const float4*)(B + (c0+jj)*ST + k4);
#pragma unroll
    for (int i = 0; i < 4; ++i)
#pragma unroll
      for (int jj = 0; jj < 4; ++jj) acc[i][jj] += dot4(a[i], b[jj]);
  }
#pragma unroll
  for (int i = 0; i < 4; ++i)
    *(float4*)(C + (r0+i)*ST + c0) =
        make_float4(acc[i][0], acc[i][1], acc[i][2], acc[i][3]);
}
// C = Base - A @ B^T (Base LDS)
__device__ __forceinline__ void w44_rr_sub(const float* A, const float* B,
                                           const float* Base, float* C, int lane) {
  const int r0 = (lane >> 3) * 4, c0 = (lane & 7) * 4, o = lane & 7;
  float acc[4][4] = {};
#pragma unroll
  for (int kk = 0; kk < 8; ++kk) {
    const int k4 = 4 * ((kk + o) & 7);
    float4 a[4], b[4];
#pragma unroll
    for (int i = 0; i < 4; ++i) a[i] = *(const float4*)(A + (r0+i)*ST + k4);
#pragma unroll
    for (int jj = 0; jj < 4; ++jj) b[jj] = *(const float4*)(B + (c0+jj)*ST + k4);
#pragma unroll
    for (int i = 0; i < 4; ++i)
#pragma unroll
      for (int jj = 0; jj < 4; ++jj) acc[i][jj] += dot4(a[i], b[jj]);
  }
#pragma unroll
  for (int i = 0; i < 4; ++i) {
    const float4 bs = *(const float4*)(Base + (r0+i)*ST + c0);
    *(float4*)(C + (r0+i)*ST + c0) =
        make_float4(bs.x - acc[i][0], bs.y - acc[i][1], bs.z - acc[i][2], bs.w - acc[i][3]);
  }
}
// C = gBase - A @ B^T (Base global stride 32)
__device__ __forceinline__ void w44_rr_subg(const float* A, const float* B,
                                            const float* __restrict__ gBase,
                                            float* C, int lane) {
  const int r0 = (lane >> 3) * 4, c0 = (lane & 7) * 4, o = lane & 7;
  float acc[4][4] = {};
#pragma unroll
  for (int kk = 0; kk < 8; ++kk) {
    const int k4 = 4 * ((kk + o) & 7);
    float4 a[4], b[4];
#pragma unroll
    for (int i = 0; i < 4; ++i) a[i] = *(const float4*)(A + (r0+i)*ST + k4);
#pragma unroll
    for (int jj = 0; jj < 4; ++jj) b[jj] = *(const float4*)(B + (c0+jj)*ST + k4);
#pragma unroll
    for (int i = 0; i < 4; ++i)
#pragma unroll
      for (int jj = 0; jj < 4; ++jj) acc[i][jj] += dot4(a[i], b[jj]);
  }
#pragma unroll
  for (int i = 0; i < 4; ++i) {
    const float4 bs = *(const float4*)(gBase + (r0+i)*32 + c0);
    *(float4*)(C + (r0+i)*ST + c0) =
        make_float4(bs.x - acc[i][0], bs.y - acc[i][1], bs.z - acc[i][2], bs.w - acc[i][3]);
  }
}
// C = A @ B (plain)
__device__ __forceinline__ void w44_p(const float* A, const float* B, float* C, int lane) {
  const int r0 = (lane >> 3) * 4, c0 = (lane & 7) * 4, o = lane & 7;
  float acc[4][4] = {};
#pragma unroll
  for (int kk = 0; kk < 8; ++kk) {
    const int k4 = 4 * ((kk + o) & 7);
    float4 a[4];
#pragma unroll
    for (int i = 0; i < 4; ++i) a[i] = *(const float4*)(A + (r0+i)*ST + k4);
#pragma unroll
    for (int e = 0; e < 4; ++e) {
      const float4 b = *(const float4*)(B + (k4+e)*ST + c0);
#pragma unroll
      for (int i = 0; i < 4; ++i) {
        const float av = f4c(a[i], e);
        acc[i][0] += av*b.x; acc[i][1] += av*b.y; acc[i][2] += av*b.z; acc[i][3] += av*b.w;
      }
    }
  }
#pragma unroll
  for (int i = 0; i < 4; ++i)
    *(float4*)(C + (r0+i)*ST + c0) =
        make_float4(acc[i][0], acc[i][1], acc[i][2], acc[i][3]);
}
// C = Base - A @ B
__device__ __forceinline__ void w44_p_sub(const float* A, const float* B,
                                          const float* Base, float* C, int lane) {
  const int r0 = (lane >> 3) * 4, c0 = (lane & 7) * 4, o = lane & 7;
  float acc[4][4] = {};
#pragma unroll
  for (int kk = 0; kk < 8; ++kk) {
    const int k4 = 4 * ((kk + o) & 7);
    float4 a[4];
#pragma unroll
    for (int i = 0; i < 4; ++i) a[i] = *(const float4*)(A + (r0+i)*ST + k4);
#pragma unroll
    for (int e = 0; e < 4; ++e) {
      const float4 b = *(const float4*)(B + (k4+e)*ST + c0);
#pragma unroll
      for (int i = 0; i < 4; ++i) {
        const float av = f4c(a[i], e);
        acc[i][0] += av*b.x; acc[i][1] += av*b.y; acc[i][2] += av*b.z; acc[i][3] += av*b.w;
      }
    }
  }
#pragma unroll
  for (int i = 0; i < 4; ++i) {
    const float4 bs = *(const float4*)(Base + (r0+i)*ST + c0);
    *(float4*)(C + (r0+i)*ST + c0) =
        make_float4(bs.x - acc[i][0], bs.y - acc[i][1], bs.z - acc[i][2], bs.w - acc[i][3]);
  }
}
// C = A^T @ B
__device__ __forceinline__ void w44_tp(const float* A, const float* B, float* C, int lane) {
  const int r0 = (lane >> 3) * 4, c0 = (lane & 7) * 4, o = lane & 7;
  float acc[4][4] = {};
#pragma unroll
  for (int kk = 0; kk < 8; ++kk) {
    const int k4 = 4 * ((kk + o) & 7);
#pragma unroll
    for (int e = 0; e < 4; ++e) {
      const int k = k4 + e;
      const float4 av = *(const float4*)(A + k*ST + r0);
      const float4 bv = *(const float4*)(B + k*ST + c0);
      acc[0][0] += av.x*bv.x; acc[0][1] += av.x*bv.y; acc[0][2] += av.x*bv.z; acc[0][3] += av.x*bv.w;
      acc[1][0] += av.y*bv.x; acc[1][1] += av.y*bv.y; acc[1][2] += av.y*bv.z; acc[1][3] += av.y*bv.w;
      acc[2][0] += av.z*bv.x; acc[2][1] += av.z*bv.y; acc[2][2] += av.z*bv.z; acc[2][3] += av.z*bv.w;
      acc[3][0] += av.w*bv.x; acc[3][1] += av.w*bv.y; acc[3][2] += av.w*bv.z; acc[3][3] += av.w*bv.w;
    }
  }
#pragma unroll
  for (int i = 0; i < 4; ++i)
    *(float4*)(C + (r0+i)*ST + c0) =
        make_float4(acc[i][0], acc[i][1], acc[i][2], acc[i][3]);
}
// C = A^T @ B + AddL
__device__ __forceinline__ void w44_tp_addL(const float* A, const float* B,
                                            const float* AddL, float* C, int lane) {
  const int r0 = (lane >> 3) * 4, c0 = (lane & 7) * 4, o = lane & 7;
  float acc[4][4] = {};
#pragma unroll
  for (int kk = 0; kk < 8; ++kk) {
    const int k4 = 4 * ((kk + o) & 7);
#pragma unroll
    for (int e = 0; e < 4; ++e) {
      const int k = k4 + e;
      const float4 av = *(const float4*)(A + k*ST + r0);
      const float4 bv = *(const float4*)(B + k*ST + c0);
      acc[0][0] += av.x*bv.x; acc[0][1] += av.x*bv.y; acc[0][2] += av.x*bv.z; acc[0][3] += av.x*bv.w;
      acc[1][0] += av.y*bv.x; acc[1][1] += av.y*bv.y; acc[1][2] += av.y*bv.z; acc[1][3] += av.y*bv.w;
      acc[2][0] += av.z*bv.x; acc[2][1] += av.z*bv.y; acc[2][2] += av.z*bv.z; acc[2][3] += av.z*bv.w;
      acc[3][0] += av.w*bv.x; acc[3][1] += av.w*bv.y; acc[3][2] += av.w*bv.z; acc[3][3] += av.w*bv.w;
    }
  }
#pragma unroll
  for (int i = 0; i < 4; ++i) {
    const float4 ad = *(const float4*)(AddL + (r0+i)*ST + c0);
    *(float4*)(C + (r0+i)*ST + c0) =
        make_float4(ad.x + acc[i][0], ad.y + acc[i][1], ad.z + acc[i][2], ad.w + acc[i][3]);
  }
}
// C = Tk @ X^T + 0.5(XC1 + XC1^T) + EMM  (ksa/ksc epilogue)
__device__ __forceinline__ void w44_epi(const float* Tk, const float* X,
                                        const float* XC1, const float* EMM,
                                        float* C, int lane) {
  const int r0 = (lane >> 3) * 4, c0 = (lane & 7) * 4, o = lane & 7;
  float acc[4][4] = {};
#pragma unroll
  for (int kk = 0; kk < 8; ++kk) {
    const int k4 = 4 * ((kk + o) & 7);
    float4 a[4], b[4];
#pragma unroll
    for (int i = 0; i < 4; ++i) a[i] = *(const float4*)(Tk + (r0+i)*ST + k4);
#pragma unroll
    for (int jj = 0; jj < 4; ++jj) b[jj] = *(const float4*)(X + (c0+jj)*ST + k4);
#pragma unroll
    for (int i = 0; i < 4; ++i)
#pragma unroll
      for (int jj = 0; jj < 4; ++jj) acc[i][jj] += dot4(a[i], b[jj]);
  }
  float4 xt[4];
#pragma unroll
  for (int jj = 0; jj < 4; ++jj) xt[jj] = *(const float4*)(XC1 + (c0+jj)*ST + r0);
#pragma unroll
  for (int i = 0; i < 4; ++i) {
    const float4 xc = *(const float4*)(XC1 + (r0+i)*ST + c0);
    const float4 em = *(const float4*)(EMM + (r0+i)*ST + c0);
    float4 v;
    v.x = acc[i][0] + 0.5f*(xc.x + f4c(xt[0], i)) + em.x;
    v.y = acc[i][1] + 0.5f*(xc.y + f4c(xt[1], i)) + em.y;
    v.z = acc[i][2] + 0.5f*(xc.z + f4c(xt[2], i)) + em.z;
    v.w = acc[i][3] + 0.5f*(xc.w + f4c(xt[3], i)) + em.w;
    *(float4*)(C + (r0+i)*ST + c0) = v;
  }
}
// C = mtw(LDS) @ Xg^T(global stride 32) - I
__device__ __forceinline__ void w44_jb(const float* mtwL, const float* __restrict__ Xg,
                                       float* C, int lane) {
  const int r0 = (lane >> 3) * 4, c0 = (lane & 7) * 4, o = lane & 7;
  float acc[4][4] = {};
#pragma unroll
  for (int kk = 0; kk < 8; ++kk) {
    const int k4 = 4 * ((kk + o) & 7);
    float4 a[4], b[4];
#pragma unroll
    for (int i = 0; i < 4; ++i) a[i] = *(const float4*)(mtwL + (r0+i)*ST + k4);
#pragma unroll
    for (int jj = 0; jj < 4; ++jj) b[jj] = *(const float4*)(Xg + (c0+jj)*32 + k4);
#pragma unroll
    for (int i = 0; i < 4; ++i)
#pragma unroll
      for (int jj = 0; jj < 4; ++jj) acc[i][jj] += dot4(a[i], b[jj]);
  }
#pragma unroll
  for (int i = 0; i < 4; ++i) {
    float4 v = make_float4(acc[i][0], acc[i][1], acc[i][2], acc[i][3]);
    v.x -= (r0+i == c0    ) ? 1.f : 0.f;
    v.y -= (r0+i == c0 + 1) ? 1.f : 0.f;
    v.z -= (r0+i == c0 + 2) ? 1.f : 0.f;
    v.w -= (r0+i == c0 + 3) ? 1.f : 0.f;
    *(float4*)(C + (r0+i)*ST + c0) = v;
  }
}

// ---------------- hierarchical grid barrier ----------------
__device__ __forceinline__ void gridbar(unsigned* base, int idx, int blk) {
  __syncthreads();
  if (threadIdx.x == 0) {
    const int g = blk & (NGRP-1);
    unsigned* lcl  = base + idx*128 + g*16;
    unsigned* go   = base + 2048 + idx*128 + g*16;
    unsigned* glob = base + 4096 + idx*16;
    __threadfence();
    __hip_atomic_fetch_add(lcl, 1u, __ATOMIC_RELEASE, __HIP_MEMORY_SCOPE_AGENT);
    if (blk < NGRP) {
      while (__hip_atomic_load(lcl, __ATOMIC_ACQUIRE, __HIP_MEMORY_SCOPE_AGENT)
             < (unsigned)GSZ)
        __builtin_amdgcn_s_sleep(1);
      __hip_atomic_fetch_add(glob, 1u, __ATOMIC_RELEASE, __HIP_MEMORY_SCOPE_AGENT);
      while (__hip_atomic_load(glob, __ATOMIC_ACQUIRE, __HIP_MEMORY_SCOPE_AGENT)
             < (unsigned)NGRP)
        __builtin_amdgcn_s_sleep(1);
      __hip_atomic_store(go, 1u, __ATOMIC_RELEASE, __HIP_MEMORY_SCOPE_AGENT);
    } else {
      while (__hip_atomic_load(go, __ATOMIC_ACQUIRE, __HIP_MEMORY_SCOPE_AGENT) == 0u)
        __builtin_amdgcn_s_sleep(1);
    }
  }
  __syncthreads();
}

// ---------------- k2 body (block 0) ----------------
__device__ void dev_k2(const float* __restrict__ obs, const float* __restrict__ vpm,
                       const float* __restrict__ vtw, const float* __restrict__ vtb,
                       const float* __restrict__ vew, const float* __restrict__ veb,
                       const float* __restrict__ mtw, const float* __restrict__ mew,
                       float* __restrict__ ws, int tid) {
  const int j = tid & 31, r0 = tid >> 5;
#pragma unroll
  for (int m = 0; m < 4; ++m) {
    const int ri = r0 + 8*m;
    float s1 = 0.f, s2 = 0.f, s3 = 0.f, s4 = 0.f;
    for (int k = 0; k < 32; ++k) {
      s1 += ws[WS_QI  + ri*32 + k] * vtw[k*32 + j];
      s2 += vew[k*32 + ri] * ws[WS_RI + k*32 + j];
      s3 += ws[WS_MTP + ri*32 + k] * mtw[k*32 + j];
      s4 += ws[WS_MEP + ri*32 + k] * mew[k*32 + j];
    }
    ws[WS_QIW + ri*32 + j] = s1;
    ws[WS_HTRI + ri*32 + j] = s2;
    ws[WS_FPT + ri*32 + j] = s3;      // temp Mtp@mtw
    ws[WS_EML + ri*32 + j] = -0.5f * s4;
  }
  __syncthreads();
#pragma unroll
  for (int m = 0; m < 4; ++m) {
    const int ri = r0 + 8*m;
    float s1 = 0.f, s2 = 0.f, s3 = 0.f, s4 = 0.f;
    for (int k = 0; k < 32; ++k) {
      s1 += vtw[k*32 + ri] * ws[WS_QIW + k*32 + j];
      s2 += ws[WS_HTRI + ri*32 + k] * vew[k*32 + j];
      s3 += mtw[k*32 + ri] * ws[WS_FPT + k*32 + j];
      s4 += mew[k*32 + ri] * ws[WS_EML + k*32 + j];
    }
    ws[WS_CW + ri*32 + j] = s1;
    ws[WS_HTRIH + ri*32 + j] = s2;
    ws[WS_LAM0CW + ri*32 + j] = ws[WS_P0I + ri*32 + j] + s1 + s2;
    ws[WS_QHC    + ri*32 + j] = ws[WS_QI  + ri*32 + j] + s1 + s2;
    ws[WS_TQ + ri*32 + j] = s3;
    ws[WS_EM + ri*32 + j] = s4;
    ws[WS_S1 + ri*32 + j] = s4 - 0.5f * ws[WS_MPP + ri*32 + j];
    ws[WS_C1 + ri*32 + j] = ws[WS_FPT + j*32 + ri];
    ws[WS_EMM + ri*32 + j] = s4 - 0.5f * ws[WS_MTP + ri*32 + j];
  }
  if (tid < 32) {
    float s1 = 0.f, s2 = 0.f, s3 = 0.f;
    for (int k = 0; k < 32; ++k) {
      s1 += ws[WS_QIW + k*32 + tid] * vtb[k];
      s2 += ws[WS_P0I + tid*32 + k] * vpm[k]
          + ws[WS_HTRI + tid*32 + k] * (obs[k] - veb[k]);
      s3 += ws[WS_QI + tid*32 + k] * vtb[k];
    }
    ws[WS_CTB + tid] = s1;
    ws[WS_ETA0 + tid] = s2;
    ws[WS_QIVTB + tid] = s3;
  }
  __syncthreads();
  if (tid == 0) {
    const double ldmt = (double)ws[WS_LDS3 + 0];
    const double ldme = (double)ws[WS_LDS3 + 1];
    const double ldmp = (double)ws[WS_LDS3 + 2];
    const double ct_me = -0.5 * (32.0 * LOG2PI + ldme);
    const double ct_mt = -0.5 * (32.0 * LOG2PI + ldmt);
    const double ct_mp = -0.5 * (32.0 * LOG2PI + ldmp);
    double c = ct_mp + ct_me;
    c += (double)(TT - 1) * (ct_me + ct_mt + 0.5 * 32.0 * LOG2PI + 16.0);
    c += 0.5 * 32.0 * LOG2PI + 16.0;
    ((double*)(ws + WS_DACC))[0] = c;
  }
  __syncthreads();
}

// ---------------- Riccati operator squaring (block 0, wave-dispatched) ----------------
__device__ void dev_compose(float* __restrict__ ws, float* sm, int tid) {
  float *Kc = sm,      *Ac = sm+MS,   *Gc = sm+2*MS;
  float *Kn = sm+3*MS, *An = sm+4*MS, *Gn = sm+5*MS;
  float *Mi = sm+6*MS, *V1 = sm+7*MS, *Wm = sm+8*MS;
  const int wv = tid >> 6, lane = tid & 63;
  stage_mat(ws + WS_QHC, Kc, tid);
  stage_mat(ws + WS_QIW, Ac, tid);
  for (int e = tid; e < MS; e += 256) Gc[e] = 0.f;
  __syncthreads();
  for (int d = 0; d < 8; ++d) {
    for (int e = tid; e < MS; e += 256) Mi[e] = Kc[e] + Gc[e];
    __syncthreads();
    if (tid < 64) wave_inv36(Mi, tid);
    __syncthreads();
    if (wv == 0) w44_rr(Ac, Mi, V1, lane);        // A M^-1 (M^-1 sym)
    else if (wv == 1) w44_tp(Ac, Mi, Wm, lane);   // A^T M^-1
    __syncthreads();
    if (wv == 0) w44_rr_sub(V1, Ac, Kc, Kn, lane);   // K' = K - A M^-1 A^T
    else if (wv == 1) w44_p(V1, Ac, An, lane);       // A' = A M^-1 A
    else if (wv == 2) w44_p_sub(Wm, Ac, Gc, Gn, lane); // G' = G - A^T M^-1 A
    __syncthreads();
    float* tp;
    tp=Kc; Kc=Kn; Kn=tp;  tp=Ac; Ac=An; An=tp;  tp=Gc; Gc=Gn; Gn=tp;
    if (d >= 2) {
      float* op = ws + WS_OPS + (d-2)*3072;
      destage_mat(Kc, op, tid);
      destage_mat(Ac, op + 1024, tid);
      destage_mat(Gc, op + 2048, tid);
    }
  }
}

// ---------------- eta machinery (unchanged — shadowed by S side) ----------------
__device__ void dev_keta_a(float* __restrict__ ws, float* sm, int tid, int c) {
  float *Aa = sm, *Ab = sm+MS, *Xl = sm+2*MS, *bb = sm+3*MS;
  const int t1 = CH*c + 1;
  stage_mat(ws + WS_X + t1*1024, Aa, tid);
  if (tid < 32) bb[tid] = ws[WS_YT + t1*32 + tid];
  __syncthreads();
  float *Acur = Aa, *Anew = Ab; int pb = 0;
  for (int t = t1 + 1; t <= t1 + CH - 1; ++t) {
    stage_mat(ws + WS_X + t*1024, Xl, tid);
    __syncthreads();
    mm_p(Xl, Acur, Anew, tid);
    if (tid < 32) {
      float s = ws[WS_YT + t*32 + tid];
      for (int k = 0; k < 32; ++k) s += Xl[tid*ST+k] * bb[pb*32 + k];
      bb[(pb^1)*32 + tid] = s;
    }
    __syncthreads();
    float* tp = Acur; Acur = Anew; Anew = tp; pb ^= 1;
  }
  float* dst = ws + WS_ETA_A + (c+1)*1056;
  destage_mat(Acur, dst, tid);
  if (tid < 32) dst[1024 + tid] = bb[pb*32 + tid];
}

__device__ void dev_eta_lvl8(float* __restrict__ ws, float* sm, int tid, int c) {
  const float* in = ws + WS_ETA_A;
  float* out = ws + WS_ETA_B;
  float *AR0 = sm, *AR1 = sm+MS, *A0 = sm+2*MS;
  float *bv = sm+3*MS, *b0 = bv + 64;
  stage_mat(in + c*1056, AR0, tid);
  if (tid < 32) bv[tid] = in[c*1056 + 1024 + tid];
  __syncthreads();
  float *AR = AR0, *At = AR1; int pb = 0;
  for (int kk = 1; kk <= 7; ++kk) {
    const int idx = c - kk;
    if (idx < 0) break;
    stage_mat(in + idx*1056, A0, tid);
    if (tid < 32) b0[tid] = in[idx*1056 + 1024 + tid];
    __syncthreads();
    mm_p(AR, A0, At, tid);
    if (tid < 32) {
      float s = bv[pb*32 + tid];
      for (int k = 0; k < 32; ++k) s += AR[tid*ST+k] * b0[k];
      bv[(pb^1)*32 + tid] = s;
    }
    __syncthreads();
    float* tp = AR; AR = At; At = tp; pb ^= 1;
  }
  destage_mat(AR, out + c*1056, tid);
  if (tid < 32) out[c*1056 + 1024 + tid] = bv[pb*32 + tid];
}

__device__ void dev_keta_b(float* __restrict__ ws, float* sm, int tid, int c) {
  float *A_0 = sm, *A_1 = sm+MS, *A_2 = sm+2*MS;
  float *bb = sm+3*MS;
  stage_mat(ws + WS_ETA_B + c*1056, A_0, tid);
  if (tid < 32) bb[tid] = ws[WS_ETA_B + c*1056 + 1024 + tid];
  __syncthreads();
  float *AR = A_0, *Ax = A_1; int pb = 0;
  for (int kk = 1; kk <= 7; ++kk) {
    const int idx = c - 8*kk;
    if (idx < 0) break;
    stage_mat(ws + WS_ETA_B + idx*1056, A_2, tid);
    if (tid < 32) bb[64 + tid] = ws[WS_ETA_B + idx*1056 + 1024 + tid];
    __syncthreads();
    mm_p(AR, A_2, Ax, tid);
    if (tid < 32) {
      float s = bb[pb*32 + tid];
      for (int k = 0; k < 32; ++k) s += AR[tid*ST+k] * bb[64+k];
      bb[(pb^1)*32 + tid] = s;
    }
    __syncthreads();
    float* tp = AR; AR = Ax; Ax = tp; pb ^= 1;
  }
  float *zeta = bb + 96, *zn = bb + 128;
  if (tid < 32) {
    float s = bb[pb*32 + tid];
    for (int k = 0; k < 32; ++k)
      s += AR[tid*ST+k] * (ws[WS_ETA0 + k] - ws[WS_CTB + k]);
    zeta[tid] = s;
  }
  __syncthreads();
  float *Bl = A_0, *Xl = A_1;
  const int nst = (c == NCH-1) ? CH-1 : CH;
  for (int i = 0; i < nst; ++i) {
    const int t = CH*c + 1 + i;
    stage_mat(ws + WS_BCOV + t*1024, Bl, tid);
    stage_mat(ws + WS_X + t*1024, Xl, tid);
    __syncthreads();
    if (tid < 32) {
      float s = 0.f;
      for (int k = 0; k < 32; ++k) s += Bl[tid*ST+k] * zeta[k];
      ws[WS_BA + t*32 + tid] = s;
    } else if (tid < 64) {
      const int i2 = tid - 32;
      float s = ws[WS_YT + t*32 + i2];
      for (int k = 0; k < 32; ++k) s += Xl[i2*ST+k] * zeta[k];
      zn[i2] = s;
    }
    __syncthreads();
    if (tid < 32) zeta[tid] = zn[tid];
    __syncthreads();
  }
  if (c == NCH-1 && tid < 32)
    ws[WS_ETAF + tid] = zeta[tid] + ws[WS_CTB + tid];
}

// ---------------- S machinery (w44) ----------------
__device__ void dev_ksa(float* __restrict__ ws, float* sm, int tid, int c) {
  float *BTa=sm,      *BTb=sm+MS,   *Ka=sm+2*MS,  *Kb=sm+3*MS,
        *Tk=sm+4*MS,  *XC1=sm+5*MS, *Xl=sm+6*MS,  *KmTQ=sm+7*MS,
        *TQl=sm+8*MS, *EMMl=sm+9*MS,*C1l=sm+10*MS;
  const int t1 = CH*c + 1, t2 = CH*c + CH;
  const int wv = tid >> 6, lane = tid & 63;
  stage_mat(ws + WS_TQ, TQl, tid);
  stage_mat(ws + WS_EMM, EMMl, tid);
  stage_mat(ws + WS_C1, C1l, tid);
  for (int e = tid; e < MS; e += 256) {
    const int r = e / ST, cc = e - ST*r;
    BTa[e] = (cc < 32 && cc == r) ? 1.f : 0.f;
    Ka[e] = 0.f;
  }
  __syncthreads();
  float *BTc = BTa, *BTn = BTb, *Kc = Ka, *Kn = Kb;
  for (int t = t1; t <= t2; ++t) {
    stage_mat(ws + WS_X + t*1024, Xl, tid);
    for (int e = tid; e < MS; e += 256) KmTQ[e] = Kc[e] - 0.5f * TQl[e];
    __syncthreads();
    if (wv == 0) w44_rr(BTc, Xl, BTn, lane);        // BT' = BT X^T
    else if (wv == 1) w44_rr(Xl, KmTQ, Tk, lane);   // X (K-.5TQ)  (sym)
    else if (wv == 2) w44_p(Xl, C1l, XC1, lane);    // X C1
    __syncthreads();
    if (wv == 0) w44_epi(Tk, Xl, XC1, EMMl, Kn, lane);
    __syncthreads();
    float* tp = BTc; BTc = BTn; BTn = tp;
    tp = Kc; Kc = Kn; Kn = tp;
  }
  float* dst = ws + WS_CEA + (c+1)*2048;
  destage_mat(BTc, dst, tid);
  destage_mat(Kc, dst + 1024, tid);
}

__device__ void dev_ks_lvl8(float* __restrict__ ws, float* sm, int tid, int c) {
  const float* in = ws + WS_CEA;
  float* out = ws + WS_CEB;
  float *BT0=sm, *BT1=sm+MS, *K0=sm+2*MS, *K1=sm+3*MS,
        *BTo=sm+4*MS, *Ko=sm+5*MS, *tmp=sm+6*MS;
  const int wv = tid >> 6, lane = tid & 63;
  stage_mat(in + c*2048, BT0, tid);
  stage_mat(in + c*2048 + 1024, K0, tid);
  __syncthreads();
  float *BTR=BT0, *BTt=BT1, *KR=K0, *Kt=K1;
  for (int kk = 1; kk <= 7; ++kk) {
    const int idx = c - kk;
    if (idx < 0) break;
    stage_mat(in + idx*2048, BTo, tid);
    stage_mat(in + idx*2048 + 1024, Ko, tid);
    __syncthreads();
    if (wv == 0) w44_p(Ko, BTR, tmp, lane);
    else if (wv == 1) w44_p(BTo, BTR, BTt, lane);
    __syncthreads();
    if (wv == 0) w44_tp_addL(BTR, tmp, KR, Kt, lane);
    __syncthreads();
    float* tp = BTR; BTR = BTt; BTt = tp;
    tp = KR; KR = Kt; Kt = tp;
  }
  destage_mat(BTR, out + c*2048, tid);
  destage_mat(KR, out + c*2048 + 1024, tid);
}

__device__ void dev_ksc(float* __restrict__ ws, float* sm, float* red,
                        int tid, int c) {
  float *BT0=sm, *BT1=sm+MS, *K0=sm+2*MS, *K1=sm+3*MS,
        *BTo=sm+4*MS, *Ko=sm+5*MS, *tmp=sm+6*MS;
  const int wv = tid >> 6, lane = tid & 63;
  stage_mat(ws + WS_CEB + c*2048, BT0, tid);
  stage_mat(ws + WS_CEB + c*2048 + 1024, K0, tid);
  __syncthreads();
  float *BTR=BT0, *BTt=BT1, *KR=K0, *Kt=K1;
  for (int kk = 1; kk <= 7; ++kk) {
    const int idx = c - 8*kk;
    if (idx < 0) break;
    stage_mat(ws + WS_CEB + idx*2048, BTo, tid);
    stage_mat(ws + WS_CEB + idx*2048 + 1024, Ko, tid);
    __syncthreads();
    if (wv == 0) w44_p(Ko, BTR, tmp, lane);
    else if (wv == 1) w44_p(BTo, BTR, BTt, lane);
    __syncthreads();
    if (wv == 0) w44_tp_addL(BTR, tmp, KR, Kt, lane);
    __syncthreads();
    float* tp = BTR; BTR = BTt; BTt = tp;
    tp = KR; KR = Kt; Kt = tp;
  }
  float *TQl=sm+7*MS, *EMMl=sm+8*MS, *C1l=sm+9*MS,
        *S=sm+10*MS, *SmTQ=sm+11*MS, *XC1=sm+12*MS;
  float *T1=tmp, *Xl=BTo, *Bcl=Ko;
  const int j = tid & 31, r0q = tid >> 5;
  stage_mat(ws + WS_TQ, TQl, tid);
  stage_mat(ws + WS_EMM, EMMl, tid);
  stage_mat(ws + WS_C1, C1l, tid);
  stage_mat(ws + WS_S1, SmTQ, tid);   // S0 temp
  __syncthreads();
  if (wv == 0) w44_p(SmTQ, BTR, T1, lane);        // S0 B_P^T
  __syncthreads();
  if (wv == 0) w44_tp_addL(BTR, T1, KR, S, lane); // S = B_P T1 + K_P
  __syncthreads();
  double accd = 0.0;
  for (int i = 0; i < CH; ++i) {
    const int t = CH*c + 1 + i;
    if (t >= TT) break;
    stage_mat(ws + WS_X + t*1024, Xl, tid);
    stage_mat(ws + WS_BCOV + t*1024, Bcl, tid);
#pragma unroll
    for (int m = 0; m < 4; ++m) {
      const int ri = r0q + 8*m;
      SmTQ[ri*ST+j] = S[ri*ST+j] - 0.5f * TQl[ri*ST+j];
    }
    __syncthreads();
    float part = 0.f;
#pragma unroll
    for (int m = 0; m < 4; ++m) {
      const int ri = r0q + 8*m;
      part += SmTQ[ri*ST+j] * Bcl[ri*ST+j];
    }
    const float r2 = block_reduce(part, red, tid);
    if (tid == 0) accd += (double)r2;
    if (wv == 0) w44_rr(Xl, SmTQ, T1, lane);   // X (S-.5TQ)  (sym)
    else if (wv == 1) w44_p(Xl, C1l, XC1, lane);
    __syncthreads();
    if (wv == 0) w44_epi(T1, Xl, XC1, EMMl, S, lane);
    __syncthreads();
  }
  if (tid == 0) ((double*)(ws + WS_PART))[64 + c] = accd;
}

// ---------------- G machinery ----------------
__device__ void dev_kga(float* __restrict__ ws, float* sm, int tid, int c) {
  float *ATa = sm, *ATb = sm+MS, *Xl = sm+2*MS, *bb = sm+3*MS;
  const int t1 = CH*c + 1;
  const int t2 = (CH*c + CH < TT) ? CH*c + CH : TT - 1;
  stage_mat(ws + WS_X + t2*1024, ATa, tid);
  if (tid < 32) bb[tid] = ws[WS_BA + t2*32 + tid];
  __syncthreads();
  float *ATc = ATa, *ATn = ATb;
  int pb = 0;
  for (int t = t2 - 1; t >= t1; --t) {
    stage_mat(ws + WS_X + t*1024, Xl, tid);
    __syncthreads();
    mm_p(ATc, Xl, ATn, tid);
    if (tid < 32) {
      float s = ws[WS_BA + t*32 + tid];
      for (int k = 0; k < 32; ++k) s += Xl[k*ST+tid] * bb[pb*32 + k];
      bb[(pb^1)*32 + tid] = s;
    }
    __syncthreads();
    float* tp = ATc; ATc = ATn; ATn = tp; pb ^= 1;
  }
  float* dst = ws + WS_CEA + (c-1)*1056;
  destage_mat(ATc, dst, tid);
  if (tid < 32) dst[1024 + tid] = bb[pb*32 + tid];
}

__device__ void dev_kg_lvl8(float* __restrict__ ws, float* sm, int tid, int c) {
  const float* in = ws + WS_CEA;
  float* out = ws + WS_CEB;
  float *AR0 = sm, *AR1 = sm+MS, *ATl = sm+2*MS;
  float *bv = sm+3*MS, *bl = bv + 64;
  const int wv = tid >> 6, lane = tid & 63;
  stage_mat(in + c*1056, AR0, tid);
  if (tid < 32) bv[tid] = in[c*1056 + 1024 + tid];
  __syncthreads();
  float *AR = AR0, *At = AR1; int pb = 0;
  for (int kk = 1; kk <= 7; ++kk) {
    const int idx = c + kk;
    if (idx > NCH - 1) break;
    stage_mat(in + idx*1056, ATl, tid);
    if (tid < 32) bl[tid] = in[idx*1056 + 1024 + tid];
    __syncthreads();
    if (wv == 0) w44_p(ATl, AR, At, lane);
    else if (wv == 1 && lane < 32) {
      float s = bv[pb*32 + lane];
      for (int k = 0; k < 32; ++k) s += AR[k*ST+lane] * bl[k];
      bv[(pb^1)*32 + lane] = s;
    }
    __syncthreads();
    float* tp = AR; AR = At; At = tp; pb ^= 1;
  }
  destage_mat(AR, out + c*1056, tid);
  if (tid < 32) out[c*1056 + 1024 + tid] = bv[pb*32 + tid];
}

// kgb with wave-dispatched mms + wave-split reduction
__device__ void dev_kgb(const float* __restrict__ obs, const float* __restrict__ mpm,
                        const float* __restrict__ mtw, const float* __restrict__ mtb,
                        const float* __restrict__ mew, const float* __restrict__ meb,
                        float* __restrict__ ws, float* sm, float* red, int tid, int c) {
  float *ATa=sm,      *ATb=sm+MS,    *Xl=sm+2*MS,  *Y1=sm+3*MS,  *Y2=sm+4*MS,
        *Jb=sm+5*MS,  *M2T=sm+6*MS,  *mewl=sm+7*MS,*EmLl=sm+8*MS,
        *fPl=sm+9*MS, *Mtpl=sm+10*MS,*Mepl=sm+11*MS,*mtwl=sm+12*MS;
  float *vec = sm + 13*MS;
  float *fml=vec, *mebl=vec+32, *mtbl=vec+64, *mpml=vec+96, *yl=vec+128,
        *bal=vec+160, *gv=vec+192, *cme=vec+224, *cmo=vec+256, *bv=vec+288;
  const int wv = tid >> 6, lane = tid & 63;
  stage_mat(mew, mewl, tid);
  stage_mat(ws + WS_EML, EmLl, tid);
  stage_mat(ws + WS_FPT, fPl, tid);
  stage_mat(ws + WS_MTP, Mtpl, tid);
  stage_mat(ws + WS_MEP, Mepl, tid);
  stage_mat(mtw, mtwl, tid);
  stage_mat(ws + WS_CEB + c*1056, ATa, tid);
  if (tid < 32) {
    fml[tid] = ws[WS_FMT + tid];
    mebl[tid] = meb[tid]; mtbl[tid] = mtb[tid]; mpml[tid] = mpm[tid];
    bv[tid] = ws[WS_CEB + c*1056 + 1024 + tid];
  }
  __syncthreads();
  float *ATc = ATa, *ATo = ATb;
  int bc = 0;
  // fold G-L2 (suffix stride-8)
  for (int kk = 1; kk <= 7; ++kk) {
    const int idx = c + 8*kk;
    if (idx > NCH - 1) break;
    stage_mat(ws + WS_CEB + idx*1056, Xl, tid);
    if (tid < 32) bal[tid] = ws[WS_CEB + idx*1056 + 1024 + tid];
    __syncthreads();
    if (wv == 0) w44_p(Xl, ATc, ATo, lane);
    else if (wv == 3 && lane < 32) {
      float s = bv[bc*32 + lane];
      for (int k = 0; k < 32; ++k) s += ATc[k*ST+lane] * bal[k];
      bv[(bc^1)*32 + lane] = s;
    }
    __syncthreads();
    float* tp = ATc; ATc = ATo; ATo = tp; bc ^= 1;
  }
  double accd = 0.0;
  for (int s = CH*c + CH - 1; s >= CH*c; --s) {
    // P0: stage
    if (s < TT-1) stage_mat(ws + WS_X + (s+1)*1024, Xl, tid);
    if (s == 0)   stage_mat(ws + WS_MPP, Jb, tid);
    if (wv == 3 && lane < 32) {
      yl[lane] = obs[s*32 + lane];
      if (s >= 1) bal[lane] = ws[WS_BA + s*32 + lane];
    }
    __syncthreads();
    // P1: AT' (wv0) || Jb (wv1) || bv' (wv3)
    if (s < TT-1) {
      if (wv == 0) w44_p(ATc, Xl, ATo, lane);
      else if (wv == 3 && lane < 32) {
        float v = ws[WS_BA + (s+1)*32 + lane];
        for (int k = 0; k < 32; ++k) v += Xl[k*ST+lane] * bv[bc*32 + k];
        bv[(bc^1)*32 + lane] = v;
      }
    }
    if (s >= 1 && wv == 1) w44_jb(mtwl, ws + WS_X + s*1024, Jb, lane);
    __syncthreads();
    const float* AT = (s < TT-1) ? ATo : ATc;
    const float* bl = (s < TT-1) ? (bv + (bc^1)*32) : (bv + bc*32);
    // P2: Y1 (wv0) || Y2 (wv1) || M2T (wv2) || gv (wv3)
    if (wv == 0) w44_rr(mewl, AT, Y1, lane);
    else if (wv == 1) w44_rr(EmLl, AT, Y2, lane);
    else if (wv == 2) { if (s >= 1) w44_rr(AT, Jb, M2T, lane); }
    else if (lane < 32) {
      float g = bl[lane];
      for (int k = 0; k < 32; ++k) g += AT[k*ST+lane] * fml[k];
      gv[lane] = g;
    }
    __syncthreads();
    // P3: cme / cmo
    if (tid < 32) {
      float s1v = mebl[tid] - yl[tid];
      for (int k = 0; k < 32; ++k) s1v += mewl[tid*ST+k] * gv[k];
      cme[tid] = s1v;
      float s2v;
      if (s >= 1) {
        s2v = mtbl[tid];
        for (int k = 0; k < 32; ++k)
          s2v += Jb[tid*ST+k] * gv[k] + mtwl[tid*ST+k] * bal[k];
      } else {
        s2v = gv[tid] - mpml[tid];
      }
      cmo[tid] = s2v;
    }
    __syncthreads();
    // P4: wave-split reduction
    const float* M2Tp = (s >= 1) ? M2T : AT;
    const float* Mqp  = (s >= 1) ? Mtpl : Jb;
    float part = 0.f;
    {
      const int r0 = (lane >> 3) * 4, c0 = (lane & 7) * 4, o = lane & 7;
      if (wv == 0) {
        float acc[4][4] = {};
#pragma unroll
        for (int kk = 0; kk < 8; ++kk) {
          const int k4 = 4 * ((kk + o) & 7);
          float4 a[4], b[4];
#pragma unroll
          for (int i = 0; i < 4; ++i) a[i] = *(const float4*)(Y2 + (r0+i)*ST + k4);
#pragma unroll
          for (int jj = 0; jj < 4; ++jj) b[jj] = *(const float4*)(fPl + (c0+jj)*ST + k4);
#pragma unroll
          for (int i = 0; i < 4; ++i)
#pragma unroll
            for (int jj = 0; jj < 4; ++jj) acc[i][jj] += dot4(a[i], b[jj]);
        }
#pragma unroll
        for (int jj = 0; jj < 4; ++jj) {
          const float4 y1t = *(const float4*)(Y1 + (c0+jj)*ST + r0);
          part += acc[0][jj]*y1t.x + acc[1][jj]*y1t.y + acc[2][jj]*y1t.z + acc[3][jj]*y1t.w;
        }
      } else if (wv == 1) {
        float e1[4][4] = {}, e2[4][4] = {};
#pragma unroll
        for (int kk = 0; kk < 8; ++kk) {
          const int k4 = 4 * ((kk + o) & 7);
          float4 mq[4], m2r[4], m2c[4], fp[4];
#pragma unroll
          for (int i = 0; i < 4; ++i) {
            mq[i]  = *(const float4*)(Mqp  + (r0+i)*ST + k4);
            m2r[i] = *(const float4*)(M2Tp + (r0+i)*ST + k4);
          }
#pragma unroll
          for (int jj = 0; jj < 4; ++jj) {
            m2c[jj] = *(const float4*)(M2Tp + (c0+jj)*ST + k4);
            fp[jj]  = *(const float4*)(fPl  + (c0+jj)*ST + k4);
          }
#pragma unroll
          for (int i = 0; i < 4; ++i)
#pragma unroll
            for (int jj = 0; jj < 4; ++jj) {
              e1[i][jj] += dot4(mq[i], m2c[jj]);
              e2[i][jj] += dot4(fp[jj], m2r[i]);
            }
        }
#pragma unroll
        for (int i = 0; i < 4; ++i)
#pragma unroll
          for (int jj = 0; jj < 4; ++jj) part -= 0.5f * e1[i][jj] * e2[i][jj];
      } else if (wv == 2) {
#pragma unroll
        for (int i = 0; i < 4; ++i) {
          const float4 me = *(const float4*)(Mepl + (r0+i)*ST + c0);
          const float4 mq = *(const float4*)(Mqp  + (r0+i)*ST + c0);
          part -= 0.5f * cme[r0+i] *
                  (me.x*cme[c0] + me.y*cme[c0+1] + me.z*cme[c0+2] + me.w*cme[c0+3]);
          part -= 0.5f * cmo[r0+i] *
                  (mq.x*cmo[c0] + mq.y*cmo[c0+1] + mq.z*cmo[c0+2] + mq.w*cmo[c0+3]);
        }
      }
    }
    const float r2 = block_reduce(part, red, tid);
    if (tid == 0) accd += (double)r2;
    if (s < TT-1) { float* tp = ATc; ATc = ATo; ATo = tp; bc ^= 1; }
    __syncthreads();
  }
  if (tid == 0) ((double*)(ws + WS_PART))[128 + c] = accd;
}

// ---------------- k0: zero barrier counters ----------------
__global__ __launch_bounds__(256) void k0_init(float* __restrict__ ws) {
  unsigned* b = (unsigned*)(ws + WS_GBAR);
  for (int e = threadIdx.x; e < 4352; e += 256) b[e] = 0u;
}

// ---------------- the fused kernel ----------------
__global__ __launch_bounds__(256) void mega(
    const float* __restrict__ obs, const float* __restrict__ mpm,
    const float* __restrict__ mpc, const float* __restrict__ mtw,
    const float* __restrict__ mtb, const float* __restrict__ mtc,
    const float* __restrict__ mew, const float* __restrict__ meb,
    const float* __restrict__ mec, const float* __restrict__ vpm,
    const float* __restrict__ vpc, const float* __restrict__ vtw,
    const float* __restrict__ vtb, const float* __restrict__ vtc,
    const float* __restrict__ vew, const float* __restrict__ veb,
    const float* __restrict__ vcc, float* __restrict__ ws,
    float* __restrict__ out) {
  __shared__ __align__(16) float sm[15360];
  __shared__ float red[4];
  const int tid = threadIdx.x, blk = blockIdx.x;
  const int wv = tid >> 6, lane = tid & 63;
  unsigned* bars = (unsigned*)(ws + WS_GBAR);
  double* P = (double*)(ws + WS_PART);
  int bix = 0;

  // ---- B0: 6 constant SPD inverses ----
  if (blk < 6) {
    const float* src = blk==0?mtc : blk==1?mec : blk==2?mpc : blk==3?vtc : blk==4?vcc : vpc;
    float* dst = ws + (blk==0?WS_MTP : blk==1?WS_MEP : blk==2?WS_MPP :
                       blk==3?WS_QI  : blk==4?WS_RI  : WS_P0I);
    if (tid < 64) {
      float a[32]; const int cc = tid & 31;
#pragma unroll
      for (int r = 0; r < 32; ++r)
        a[r] = (tid < 32) ? src[r*32 + cc] : ((r == tid - 32) ? 1.f : 0.f);
      const double pp = gj_inv32(a);
      if (tid >= 32) {
        const int c2 = tid - 32;
#pragma unroll
        for (int r = 0; r < 32; ++r) dst[r*32 + c2] = a[r];
      }
      if (tid == 0 && blk < 3) ws[WS_LDS3 + blk] = (float)log(pp);
    }
  }
  gridbar(bars, bix++, blk);   // 0

  // ---- B1: derived constants + operator squarings (blk0) ----
  if (blk == 0) {
    dev_k2(obs, vpm, vtw, vtb, vew, veb, mtw, mew, ws, tid);
    dev_compose(ws, sm, tid);
  }
  gridbar(bars, bix++, blk);   // 1

  // ---- B2: boundary + chunk expansion (blk<64) || YT (blk>=64) ----
  if (blk < NCH) {
    float *Zl=sm, *Mi=sm+MS, *Aol=sm+2*MS, *V1=sm+3*MS;
    float *Bcv=sm+4*MS, *Xs=sm+5*MS, *QiWl=sm+6*MS, *QHCl=sm+7*MS;
    const int c = blk;
    stage_mat(ws + WS_LAM0CW, Zl, tid);
    stage_mat(ws + WS_QIW, QiWl, tid);
    stage_mat(ws + WS_QHC, QHCl, tid);
    __syncthreads();
    for (int k = 0; k < 6; ++k) {
      if (!((c >> k) & 1)) continue;
      const float* OP = ws + WS_OPS + k*3072;
      {
        const int r = tid >> 3, c4 = (tid & 7) * 4;
        const float4 g = *(const float4*)(OP + 2048 + r*32 + c4);
        float4 z = *(const float4*)(Zl + r*ST + c4);
        z.x += g.x; z.y += g.y; z.z += g.z; z.w += g.w;
        *(float4*)(Mi + r*ST + c4) = z;
      }
      stage_mat(OP + 1024, Aol, tid);
      __syncthreads();
      if (tid < 64) wave_inv36(Mi, tid);
      __syncthreads();
      if (wv == 0) w44_rr(Aol, Mi, V1, lane);
      __syncthreads();
      if (wv == 0) w44_rr_subg(V1, Aol, OP, Zl, lane);
      __syncthreads();
    }
    const int nst = (c == NCH-1) ? CH-1 : CH;
    double acc = 0.0;
    for (int i = 0; i < nst; ++i) {
      const int t = CH*c + 1 + i;
      if (tid < 64) {
        float a[32]; const int cc = tid & 31;
#pragma unroll
        for (int r = 0; r < 32; ++r)
          a[r] = (tid < 32) ? Zl[r*ST+cc] : ((r == tid - 32) ? 1.f : 0.f);
        const double pp = gj_inv32(a);
        if (tid >= 32) {
          const int c2 = tid - 32;
#pragma unroll
          for (int r = 0; r < 32; ++r) {
            Bcv[r*ST + c2] = a[r];
            ws[WS_BCOV + t*1024 + r*32 + c2] = a[r];
          }
        }
        if (tid == 0) acc += -log(pp);
      }
      __syncthreads();
      if (wv == 0) w44_rr(QiWl, Bcv, Xs, lane);
      __syncthreads();
      destage_mat(Xs, ws + WS_X + t*1024, tid);
      if (wv == 0) w44_rr_sub(Xs, QiWl, QHCl, Zl, lane);
      __syncthreads();
    }
    if (c == NCH-1) destage_mat(Zl, ws + WS_Z512, tid);
    if (tid == 0) P[blk] = acc;
  } else {
    const int tb = blk - NCH;
    const int t = tb*CH + (tid >> 5), i = tid & 31;
    float s = ws[WS_QIVTB + i] - ws[WS_CTB + i];
    for (int k = 0; k < 32; ++k)
      s += ws[WS_HTRI + i*32 + k] * (obs[t*32 + k] - veb[k]);
    ws[WS_YT + t*32 + i] = s;
  }
  gridbar(bars, bix++, blk);   // 2

  // ---- B3: eta chunk compose (blk<64) || S chunk compose (blk>=64) ----
  if (blk < NCH) {
    if (blk < NCH-1) {
      dev_keta_a(ws, sm, tid, blk);
    } else {
      for (int e = tid; e < 1056; e += 256)
        ws[WS_ETA_A + e] = (e < 1024 && ((e >> 5) == (e & 31))) ? 1.f : 0.f;
    }
  } else {
    const int c = blk - NCH;
    if (c < NCH-1) {
      dev_ksa(ws, sm, tid, c);
    } else {
      for (int e = tid; e < 2048; e += 256)
        ws[WS_CEA + e] = (e < 1024 && ((e >> 5) == (e & 31))) ? 1.f : 0.f;
    }
  }
  gridbar(bars, bix++, blk);   // 3

  // ---- B4: radix-8 L1: eta (blk<64) || S (blk>=64) ----
  if (blk < NCH) dev_eta_lvl8(ws, sm, tid, blk);
  else           dev_ks_lvl8(ws, sm, tid, blk - NCH);
  gridbar(bars, bix++, blk);   // 4

  // ---- B5: keta_b(+fold) then kga (blk<64) || ksc(+fold) (blk>=64) ----
  if (blk < NCH) {
    dev_keta_b(ws, sm, tid, blk);
    __threadfence();
    __syncthreads();
    if (blk == 0) {
      for (int e = tid; e < 1056; e += 256)
        ws[WS_CEA + (NCH-1)*1056 + e] =
            (e < 1024 && ((e >> 5) == (e & 31))) ? 1.f : 0.f;
    } else {
      dev_kga(ws, sm, tid, blk);
    }
  } else {
    dev_ksc(ws, sm, red, tid, blk - NCH);
  }
  gridbar(bars, bix++, blk);   // 5

  // ---- B6: radix-8 G-L1 (blk<64) || kfin (blk==64) ----
  if (blk < NCH) {
    dev_kg_lvl8(ws, sm, tid, blk);
  } else if (blk == NCH) {
    if (tid < 64) {
      float a[32]; const int cc = tid & 31;
#pragma unroll
      for (int r = 0; r < 32; ++r) {
        const float v = ws[WS_Z512 + r*32 + cc] - ws[WS_CW + r*32 + cc];
        a[r] = (tid < 32) ? v : ((r == tid - 32) ? 1.f : 0.f);
      }
      const double pp = gj_inv32(a);
      if (tid >= 32) {
        const int c2 = tid - 32;
        float fmv = 0.f;
#pragma unroll
        for (int r = 0; r < 32; ++r) {
          ws[WS_FPT + r*32 + c2] = a[r];
          fmv += a[r] * ws[WS_ETAF + r];
        }
        ws[WS_FMT + c2] = fmv;
      }
      if (tid == 0) P[192] = -log(pp);
    }
  }
  gridbar(bars, bix++, blk);   // 6

  // ---- B7: kgb(+fold) (blk<64) ----
  if (blk < NCH) dev_kgb(obs, mpm, mtw, mtb, mew, meb, ws, sm, red, tid, blk);
  gridbar(bars, bix++, blk);   // 7

  // ---- out: wave-parallel partial reduction (blk0) ----
  if (blk == 0 && tid < 64) {
    double v = 0.5 * P[tid] + P[64 + tid] + P[128 + tid];
#pragma unroll
    for (int m = 32; m >= 1; m >>= 1) v += __shfl_xor(v, m, 64);
    if (tid == 0) {
      const double* d = (const double*)(ws + WS_DACC);
      out[0] = (float)(v + d[0] + 0.5 * P[192]);
    }
  }
}

extern "C" void kernel_launch(void* const* d_in, const int* in_sizes, int n_in,
                              void* d_out, int out_size, void* d_ws, size_t ws_size,
                              hipStream_t stream) {
  (void)in_sizes; (void)n_in; (void)out_size; (void)ws_size;
  const float* obs = (const float*)d_in[0];
  const float* mpm = (const float*)d_in[1];
  const float* mpc = (const float*)d_in[2];
  const float* mtw = (const float*)d_in[3];
  const float* mtb = (const float*)d_in[4];
  const float* mtc = (const float*)d_in[5];
  const float* mew = (const float*)d_in[6];
  const float* meb = (const float*)d_in[7];
  const float* mec = (const float*)d_in[8];
  const float* vpm = (const float*)d_in[9];
  const float* vpc = (const float*)d_in[10];
  const float* vtw = (const float*)d_in[11];
  const float* vtb = (const float*)d_in[12];
  const float* vtc = (const float*)d_in[13];
  const float* vew = (const float*)d_in[14];
  const float* veb = (const float*)d_in[15];
  const float* vcc = (const float*)d_in[16];
  float* ws  = (float*)d_ws;
  float* out = (float*)d_out;

  k0_init<<<1, 256, 0, stream>>>(ws);
  mega<<<NB, 256, 0, stream>>>(obs, mpm, mpc, mtw, mtb, mtc, mew, meb, mec,
                               vpm, vpc, vtw, vtb, vtc, vew, veb, vcc, ws, out);
}